// Round 2
// baseline (27198.611 us; speedup 1.0000x reference)
//
#include <hip/hip_runtime.h>

// ---------------------------------------------------------------------------
// ResRNN: sequential gated residual RNN, B=64, T=2048, D=32, H=256 (fp32).
//
// Tensor-parallel RNN, FENCE-FREE tagged exchange (R2):
//  * 64 RNN wgs = 4 row-groups (16 rows, MFMA M=16) x 16 col-slices (16 cols).
//  * Weight col-slices in LDS as bf16 MFMA B-fragments (89 KB/CU).
//  * States exchanged as tagged u32 words: (t<<16)|bf16(value), written and
//    read with RELAXED AGENT-scope atomics. Per-dword atomicity makes each
//    word self-validating -> NO fences, NO flag RMWs, NO L2 writeback/inv
//    storms (R1 post-mortem: 3 x {release wbl2 + 16 serialized fetch_adds +
//    acquire buffer_inv} per step = ~12 us/step, 470 MB HBM traffic).
//  * 4 out-wgs compute out = h2@O1 + h3@O2 + bo off the critical path from a
//    depth-32 tagged ring; 1-word monotonic done[] per rg for back-pressure.
// ---------------------------------------------------------------------------

#define T_LEN 2048
#define BATCH 64
#define DIM   32
#define HID   256
#define NRG   4
#define RING  32

typedef short frag_ab __attribute__((ext_vector_type(8)));   // 8 x bf16
typedef float frag_cd __attribute__((ext_vector_type(4)));   // 4 x f32
typedef float float4v __attribute__((ext_vector_type(4)));

#define MFMA16(a, b, c) __builtin_amdgcn_mfma_f32_16x16x32_bf16((a), (b), (c), 0, 0, 0)

// LDS slot bases (1 slot = one K-tile of B-frags = 64 lanes * 16 B = 1 KB)
#define S_W1 0
#define S_U1 1
#define S_W2 9
#define S_U2 17
#define S_W3 25
#define S_U3 33
#define S_V3 41
#define S_G1 49   // 49..56 h1-part, 57..64 h2-part
#define S_G2 65   // 65..72 h1, 73..80 h2, 81..88 h3
#define NSLOT 89
#define LDS_BYTES (NSLOT * 64 * 16)   // 91,136 B

// workspace layout (tagged u32 state words; total ~4.26 MB)
#define H1_OFF   0
#define H1_SZ    (BATCH * HID * 4)
#define H2R_OFF  (H1_OFF + H1_SZ)
#define H2R_SZ   (RING * BATCH * HID * 4)
#define H3R_OFF  (H2R_OFF + H2R_SZ)
#define H3R_SZ   (RING * BATCH * HID * 4)
#define DONE_OFF (H3R_OFF + H3R_SZ)
#define DONE_SZ  (NRG * 4)

__device__ __forceinline__ unsigned short f2bf(float f) {
  unsigned u = __builtin_bit_cast(unsigned, f);
  u = (u + 0x7FFFu + ((u >> 16) & 1u)) >> 16;   // RNE
  return (unsigned short)u;
}

__device__ __forceinline__ float fast_tanh(float x) {
  x = fminf(fmaxf(x, -15.f), 15.f);
  float e = __expf(2.f * x);
  return (e - 1.f) / (e + 1.f);
}

__device__ __forceinline__ float fast_sigmoid(float x) {
  x = fminf(fmaxf(x, -30.f), 30.f);
  return 1.f / (1.f + __expf(-x));
}

// publish 4 tagged words (rows rr, fixed col), relaxed agent scope
__device__ __forceinline__ void publish4(unsigned* pp, unsigned tag, const float* v) {
  #pragma unroll
  for (int rr = 0; rr < 4; ++rr)
    __hip_atomic_store(pp + (size_t)rr * HID, (tag << 16) | (unsigned)f2bf(v[rr]),
                       __ATOMIC_RELAXED, __HIP_MEMORY_SCOPE_AGENT);
}

// poll one state's A-fragments: lane reads row (lane&15), dwords kt*32+quad*8+j,
// retrying until every word carries `tag`. p = base + row*HID + quad*8.
__device__ __forceinline__ void poll_state(const unsigned* p, unsigned tag, frag_ab* a) {
  for (;;) {
    bool ok = true;
    #pragma unroll
    for (int kt = 0; kt < 8; ++kt) {
      #pragma unroll
      for (int j = 0; j < 8; ++j) {
        unsigned w = __hip_atomic_load(p + kt * 32 + j,
                                       __ATOMIC_RELAXED, __HIP_MEMORY_SCOPE_AGENT);
        ok &= ((w >> 16) == tag);
        a[kt][j] = (short)w;
      }
    }
    if (__all(ok)) return;
  }
}

__global__ void __launch_bounds__(64, 1)
resrnn_kernel(const float* __restrict__ x,
              const float* __restrict__ W1, const float* __restrict__ U1, const float* __restrict__ b1,
              const float* __restrict__ W2, const float* __restrict__ U2, const float* __restrict__ b2,
              const float* __restrict__ W3, const float* __restrict__ U3, const float* __restrict__ V3,
              const float* __restrict__ b3,
              const float* __restrict__ G1, const float* __restrict__ bg1,
              const float* __restrict__ G2, const float* __restrict__ bg2,
              const float* __restrict__ O1, const float* __restrict__ O2, const float* __restrict__ bo,
              float* __restrict__ out,
              unsigned* __restrict__ h1buf,   // [BATCH][HID] tagged
              unsigned* __restrict__ h2r,     // [RING][BATCH][HID] tagged
              unsigned* __restrict__ h3r,     // [RING][BATCH][HID] tagged
              unsigned* __restrict__ done)    // [NRG] monotonic step counter
{
  extern __shared__ char smem[];
  frag_ab* wf = (frag_ab*)smem;

  const int lane = (int)threadIdx.x;   // block = 1 wave of 64
  const int quad = lane >> 4;
  const int nn   = lane & 15;
  const int bid  = (int)blockIdx.x;

  if (bid < 64) {
    // ------------------------- RNN workgroup -------------------------
    const int rg = bid & 3;
    const int sl = bid >> 2;
    const int colbase = sl * 16;

    // ---- stage weights into LDS as bf16 B-fragments ----
    {
      const float* mats[9] = { W1, U1, W2, U2, W3, U3, V3, G1, G2 };
      const int    nkt[9]  = { 1, 8, 8, 8, 8, 8, 8, 16, 24 };
      int slot = 0;
      for (int m = 0; m < 9; ++m) {
        const float* W = mats[m];
        for (int kt = 0; kt < nkt[m]; ++kt) {
          frag_ab f;
          #pragma unroll
          for (int j = 0; j < 8; ++j) {
            int k = kt * 32 + quad * 8 + j;
            f[j] = (short)f2bf(W[(size_t)k * HID + colbase + nn]);
          }
          wf[slot * 64 + lane] = f;
          ++slot;
        }
      }
    }

    const float b1l  = b1[colbase + nn];
    const float b2l  = b2[colbase + nn];
    const float b3l  = b3[colbase + nn];
    const float bg1l = bg1[colbase + nn];
    const float bg2l = bg2[colbase + nn];

    frag_ab a1[8], a2[8], a3[8];
    const frag_ab zf = {0,0,0,0,0,0,0,0};
    #pragma unroll
    for (int i = 0; i < 8; ++i) { a1[i] = zf; a2[i] = zf; a3[i] = zf; }
    float h2l[4] = {0.f,0.f,0.f,0.f};
    float h3l[4] = {0.f,0.f,0.f,0.f};
    float z1l[4] = {1.f,1.f,1.f,1.f};
    float z2l[4] = {1.f,1.f,1.f,1.f};

    const float*    xrow  = x + (size_t)(rg * 16 + nn) * T_LEN * DIM + quad * 8;
    unsigned*       h1pub = h1buf + ((size_t)(rg * 16 + quad * 4)) * HID + colbase + nn;
    const unsigned* h1rd  = h1buf + ((size_t)(rg * 16 + nn)) * HID + quad * 8;

    for (int t = 0; t < T_LEN; ++t) {
      const unsigned tag  = (unsigned)t;
      const int      slot = t & (RING - 1);

      // ring back-pressure (out-wgs lag ~1 step << RING; rarely spins)
      if (t >= RING) {
        const unsigned need = (unsigned)(t - RING + 1);
        while (__hip_atomic_load(done + rg, __ATOMIC_RELAXED, __HIP_MEMORY_SCOPE_AGENT) < need) {}
      }

      // ---- stage 1: h1 = tanh(x@W1 + h1@U1 + b1) ----
      frag_cd p1a = {0.f,0.f,0.f,0.f}, p1b = {0.f,0.f,0.f,0.f};
      {
        const float* xp = xrow + (size_t)t * DIM;
        float4v xa = *(const float4v*)xp;
        float4v xb = *(const float4v*)(xp + 4);
        frag_ab xf;
        #pragma unroll
        for (int j = 0; j < 4; ++j) { xf[j] = (short)f2bf(xa[j]); xf[4 + j] = (short)f2bf(xb[j]); }
        p1a = MFMA16(xf, wf[S_W1 * 64 + lane], p1a);
      }
      #pragma unroll
      for (int kt = 0; kt < 4; ++kt) p1a = MFMA16(a1[kt], wf[(S_U1 + kt) * 64 + lane], p1a);
      #pragma unroll
      for (int kt = 4; kt < 8; ++kt) p1b = MFMA16(a1[kt], wf[(S_U1 + kt) * 64 + lane], p1b);
      {
        float v[4];
        #pragma unroll
        for (int rr = 0; rr < 4; ++rr) v[rr] = fast_tanh(p1a[rr] + p1b[rr] + b1l);
        publish4(h1pub, tag, v);
      }

      // overlap: h2@U2 with old h2 frags (independent of h1(t))
      frag_cd p2a = {0.f,0.f,0.f,0.f}, p2b = {0.f,0.f,0.f,0.f};
      #pragma unroll
      for (int kt = 0; kt < 4; ++kt) p2a = MFMA16(a2[kt], wf[(S_U2 + kt) * 64 + lane], p2a);
      #pragma unroll
      for (int kt = 4; kt < 8; ++kt) p2b = MFMA16(a2[kt], wf[(S_U2 + kt) * 64 + lane], p2b);

      poll_state(h1rd, tag, a1);   // gather full h1(t)

      // ---- stage 2: h2 = z1*tanh(h1@W2 + h2@U2 + b2) + (1-z1)*h2 ----
      #pragma unroll
      for (int kt = 0; kt < 4; ++kt) p2a = MFMA16(a1[kt], wf[(S_W2 + kt) * 64 + lane], p2a);
      #pragma unroll
      for (int kt = 4; kt < 8; ++kt) p2b = MFMA16(a1[kt], wf[(S_W2 + kt) * 64 + lane], p2b);
      #pragma unroll
      for (int rr = 0; rr < 4; ++rr) {
        float c = fast_tanh(p2a[rr] + p2b[rr] + b2l);
        h2l[rr] = z1l[rr] * c + (1.f - z1l[rr]) * h2l[rr];
      }
      publish4(h2r + ((size_t)slot * BATCH + rg * 16 + quad * 4) * HID + colbase + nn, tag, h2l);

      // overlap: h3@U3 (old h3), h1@V3, G1 h1-part (independent of h2(t))
      frag_cd p3u = {0.f,0.f,0.f,0.f}, p3v = {0.f,0.f,0.f,0.f}, pg1a = {0.f,0.f,0.f,0.f};
      #pragma unroll
      for (int kt = 0; kt < 8; ++kt) p3u = MFMA16(a3[kt], wf[(S_U3 + kt) * 64 + lane], p3u);
      #pragma unroll
      for (int kt = 0; kt < 8; ++kt) p3v = MFMA16(a1[kt], wf[(S_V3 + kt) * 64 + lane], p3v);
      #pragma unroll
      for (int kt = 0; kt < 8; ++kt) pg1a = MFMA16(a1[kt], wf[(S_G1 + kt) * 64 + lane], pg1a);

      poll_state(h2r + ((size_t)slot * BATCH + rg * 16 + nn) * HID + quad * 8, tag, a2);

      // ---- stage 3: h3 = z2*tanh(h2@W3 + h3@U3 + h1@V3 + b3) + (1-z2)*h3 ----
      frag_cd p3w = {0.f,0.f,0.f,0.f};
      #pragma unroll
      for (int kt = 0; kt < 8; ++kt) p3w = MFMA16(a2[kt], wf[(S_W3 + kt) * 64 + lane], p3w);
      #pragma unroll
      for (int rr = 0; rr < 4; ++rr) {
        float c = fast_tanh(p3u[rr] + p3v[rr] + p3w[rr] + b3l);
        h3l[rr] = z2l[rr] * c + (1.f - z2l[rr]) * h3l[rr];
      }
      publish4(h3r + ((size_t)slot * BATCH + rg * 16 + quad * 4) * HID + colbase + nn, tag, h3l);

      // overlap: G1 h2-part, G2 h1+h2 parts (independent of h3(t))
      frag_cd pg1b = {0.f,0.f,0.f,0.f}, pg2a = {0.f,0.f,0.f,0.f}, pg2b = {0.f,0.f,0.f,0.f};
      #pragma unroll
      for (int kt = 0; kt < 8; ++kt) pg1b = MFMA16(a2[kt], wf[(S_G1 + 8 + kt) * 64 + lane], pg1b);
      #pragma unroll
      for (int kt = 0; kt < 8; ++kt) pg2a = MFMA16(a1[kt], wf[(S_G2 + kt) * 64 + lane], pg2a);
      #pragma unroll
      for (int kt = 0; kt < 8; ++kt) pg2b = MFMA16(a2[kt], wf[(S_G2 + 8 + kt) * 64 + lane], pg2b);

      poll_state(h3r + ((size_t)slot * BATCH + rg * 16 + nn) * HID + quad * 8, tag, a3);

      // ---- gates ----
      frag_cd pg2c = {0.f,0.f,0.f,0.f};
      #pragma unroll
      for (int kt = 0; kt < 8; ++kt) pg2c = MFMA16(a3[kt], wf[(S_G2 + 16 + kt) * 64 + lane], pg2c);
      #pragma unroll
      for (int rr = 0; rr < 4; ++rr) {
        float z1n = fast_sigmoid(pg1a[rr] + pg1b[rr] + bg1l);
        float z2n = fast_sigmoid(pg2a[rr] + pg2b[rr] + pg2c[rr] + bg2l);
        z1l[rr] = z1n * z2n;
        z2l[rr] = z2n;
      }
    }
  } else {
    // --------------------- output-projection workgroup ---------------------
    const int rg = bid - 64;
    {
      const float* mats[2] = { O1, O2 };
      for (int m = 0; m < 2; ++m)
        for (int nt = 0; nt < 2; ++nt)
          for (int kt = 0; kt < 8; ++kt) {
            frag_ab f;
            #pragma unroll
            for (int j = 0; j < 8; ++j) {
              int k = kt * 32 + quad * 8 + j;
              f[j] = (short)f2bf(mats[m][(size_t)k * DIM + nt * 16 + nn]);
            }
            wf[(m * 16 + nt * 8 + kt) * 64 + lane] = f;
          }
    }
    const float bo0 = bo[nn];
    const float bo1 = bo[16 + nn];

    for (int t = 0; t < T_LEN; ++t) {
      const unsigned tag  = (unsigned)t;
      const int      slot = t & (RING - 1);
      const unsigned* g2p = h2r + ((size_t)slot * BATCH + rg * 16 + nn) * HID + quad * 8;
      const unsigned* g3p = h3r + ((size_t)slot * BATCH + rg * 16 + nn) * HID + quad * 8;

      frag_ab a2[8], a3[8];
      for (;;) {   // combined tagged poll of h2(t) and h3(t)
        bool ok = true;
        #pragma unroll
        for (int kt = 0; kt < 8; ++kt) {
          #pragma unroll
          for (int j = 0; j < 8; ++j) {
            unsigned w2 = __hip_atomic_load(g2p + kt * 32 + j,
                                            __ATOMIC_RELAXED, __HIP_MEMORY_SCOPE_AGENT);
            unsigned w3 = __hip_atomic_load(g3p + kt * 32 + j,
                                            __ATOMIC_RELAXED, __HIP_MEMORY_SCOPE_AGENT);
            ok &= ((w2 >> 16) == tag) & ((w3 >> 16) == tag);
            a2[kt][j] = (short)w2;
            a3[kt][j] = (short)w3;
          }
        }
        if (__all(ok)) break;
      }

      frag_cd o0 = {0.f,0.f,0.f,0.f}, o1 = {0.f,0.f,0.f,0.f};
      #pragma unroll
      for (int kt = 0; kt < 8; ++kt) {
        o0 = MFMA16(a2[kt], wf[(0 * 16 + 0 * 8 + kt) * 64 + lane], o0);
        o1 = MFMA16(a2[kt], wf[(0 * 16 + 1 * 8 + kt) * 64 + lane], o1);
        o0 = MFMA16(a3[kt], wf[(1 * 16 + 0 * 8 + kt) * 64 + lane], o0);
        o1 = MFMA16(a3[kt], wf[(1 * 16 + 1 * 8 + kt) * 64 + lane], o1);
      }
      #pragma unroll
      for (int rr = 0; rr < 4; ++rr) {
        float* op = out + ((size_t)(rg * 16 + quad * 4 + rr) * T_LEN + t) * DIM;
        op[nn]      = o0[rr] + bo0;
        op[16 + nn] = o1[rr] + bo1;
      }
      // data consumed into registers (tag-checked) -> safe to free ring slot
      if (lane == 0)
        __hip_atomic_store(done + rg, (unsigned)(t + 1),
                           __ATOMIC_RELAXED, __HIP_MEMORY_SCOPE_AGENT);
    }
  }
}

extern "C" void kernel_launch(void* const* d_in, const int* in_sizes, int n_in,
                              void* d_out, int out_size, void* d_ws, size_t ws_size,
                              hipStream_t stream)
{
  (void)in_sizes; (void)n_in; (void)out_size; (void)ws_size;

  const float* x   = (const float*)d_in[0];
  const float* W1  = (const float*)d_in[1];
  const float* U1  = (const float*)d_in[2];
  const float* b1  = (const float*)d_in[3];
  const float* W2  = (const float*)d_in[4];
  const float* U2  = (const float*)d_in[5];
  const float* b2  = (const float*)d_in[6];
  const float* W3  = (const float*)d_in[7];
  const float* U3  = (const float*)d_in[8];
  const float* V3  = (const float*)d_in[9];
  const float* b3  = (const float*)d_in[10];
  const float* G1  = (const float*)d_in[11];
  const float* bg1 = (const float*)d_in[12];
  const float* G2  = (const float*)d_in[13];
  const float* bg2 = (const float*)d_in[14];
  const float* O1  = (const float*)d_in[15];
  const float* O2  = (const float*)d_in[16];
  const float* bo  = (const float*)d_in[17];

  char* ws = (char*)d_ws;
  unsigned* h1buf = (unsigned*)(ws + H1_OFF);
  unsigned* h2r   = (unsigned*)(ws + H2R_OFF);
  unsigned* h3r   = (unsigned*)(ws + H3R_OFF);
  unsigned* done  = (unsigned*)(ws + DONE_OFF);

  // back-pressure counters must start at 0 (ws is poisoned 0xAA);
  // tagged state buffers need no init (poison tag 0xAAAA never matches)
  hipMemsetAsync(done, 0, DONE_SZ, stream);

  (void)hipFuncSetAttribute((const void*)resrnn_kernel,
                            hipFuncAttributeMaxDynamicSharedMemorySize, LDS_BYTES);

  resrnn_kernel<<<dim3(68), dim3(64), LDS_BYTES, stream>>>(
      x, W1, U1, b1, W2, U2, b2, W3, U3, V3, b3,
      G1, bg1, G2, bg2, O1, O2, bo,
      (float*)d_out, h1buf, h2r, h3r, done);
}

// Round 4
// 19948.323 us; speedup vs baseline: 1.3635x; 1.3635x over previous
//
#include <hip/hip_runtime.h>

// ---------------------------------------------------------------------------
// ResRNN: sequential gated residual RNN, B=64, T=2048, D=32, H=256 (fp32).
//
// R4: LLC-based exchange, summary-tag protocol (placement-agnostic).
//  * Topology = R2 (proven): 64 RNN wgs = 4 row-groups x 16 col-slices,
//    weights resident in LDS (89 KB), 4 out-wgs on a depth-32 ring.
//  * R2 post-mortem: per-dword AGENT-scope atomic polls = 64 scalar
//    L2-bypassing loads/lane/retry x 17 waves -> serialization at the
//    coherence point, 4.4us/hop, FETCH 610MB.
//  * R4 exchange: producers issue 4 payload stores (tagged words
//    (t+1)<<16|bf16, sc0 sc1 = LLC-visible), s_waitcnt vmcnt(0), then ONE
//    line-padded summary dword (monotonic t+1). Consumers poll 16 summary
//    dwords (1/lane), then read payload once: 16x global_load_dwordx4
//    sc0 sc1 pipelined under a single vmcnt. Embedded tags self-validate;
//    a failed check just retries -> correct under any placement/ordering.
//  * R3 lesson: no placement-dependent (XCC_ID) or unverifiable cache-op
//    (buffer_inv) protocols -- both hang paths with no fallback.
// ---------------------------------------------------------------------------

#define T_LEN 2048
#define BATCH 64
#define DIM   32
#define HID   256
#define NRG   4
#define RING  32

typedef short    frag_ab __attribute__((ext_vector_type(8)));   // 8 x bf16
typedef float    frag_cd __attribute__((ext_vector_type(4)));   // 4 x f32
typedef float    float4v __attribute__((ext_vector_type(4)));
typedef unsigned uint4v  __attribute__((ext_vector_type(4)));

#define MFMA16(a, b, c) __builtin_amdgcn_mfma_f32_16x16x32_bf16((a), (b), (c), 0, 0, 0)

// LDS slot bases (1 slot = one K-tile of B-frags = 64 lanes * 16 B = 1 KB)
#define S_W1 0
#define S_U1 1
#define S_W2 9
#define S_U2 17
#define S_W3 25
#define S_U3 33
#define S_V3 41
#define S_G1 49   // 49..56 h1-part, 57..64 h2-part
#define S_G2 65   // 65..72 h1, 73..80 h2, 81..88 h3
#define NSLOT 89
#define LDS_BYTES (NSLOT * 64 * 16)   // 91,136 B

// workspace layout (dwords unless noted)
#define H1_OFF   0
#define H1_SZ    (BATCH * HID * 4)                  // 64 KB
#define H2R_OFF  (H1_OFF + H1_SZ)
#define H2R_SZ   (RING * BATCH * HID * 4)           // 2 MB
#define H3R_OFF  (H2R_OFF + H2R_SZ)
#define H3R_SZ   (RING * BATCH * HID * 4)           // 2 MB
#define SUM_OFF  (H3R_OFF + H3R_SZ)
#define SUM_DW   (3 * NRG * 16 * 16)                // [st][rg][prod] pad 16 dw
#define DONE_DW  (NRG * 16)                         // [rg] pad 16 dw
#define CTL_SZ   ((SUM_DW + DONE_DW) * 4)           // memset region

__device__ __forceinline__ unsigned short f2bf(float f) {
  unsigned u = __builtin_bit_cast(unsigned, f);
  u = (u + 0x7FFFu + ((u >> 16) & 1u)) >> 16;   // RNE
  return (unsigned short)u;
}

__device__ __forceinline__ float fast_tanh(float x) {
  x = fminf(fmaxf(x, -15.f), 15.f);
  float e = __expf(2.f * x);
  return (e - 1.f) / (e + 1.f);
}

__device__ __forceinline__ float fast_sigmoid(float x) {
  x = fminf(fmaxf(x, -30.f), 30.f);
  return 1.f / (1.f + __expf(-x));
}

// ---- LLC-visible plain (non-atomic) memory ops ----
__device__ __forceinline__ void st_sys_u32(unsigned* p, unsigned v) {
  asm volatile("global_store_dword %0, %1, off sc0 sc1" :: "v"(p), "v"(v) : "memory");
}
__device__ __forceinline__ unsigned ld_sys_u32(const unsigned* p) {
  unsigned r;
  asm volatile("global_load_dword %0, %1, off sc0 sc1\n\t"
               "s_waitcnt vmcnt(0)"
               : "=v"(r) : "v"(p) : "memory");
  return r;
}
__device__ __forceinline__ void wait_vm0() {
  asm volatile("s_waitcnt vmcnt(0)" ::: "memory");
}

// one-shot payload read: 16 x dwordx4 (sc0 sc1) pipelined, single vmcnt.
// p = base + row*HID + quad*8 (dwords); offsets kt*128 + {0,16} bytes.
__device__ __forceinline__ void load16_sys(const unsigned* p, uint4v r[16]) {
  asm volatile(
      "global_load_dwordx4 %0, %16, off sc0 sc1\n\t"
      "global_load_dwordx4 %1, %16, off offset:16 sc0 sc1\n\t"
      "global_load_dwordx4 %2, %16, off offset:128 sc0 sc1\n\t"
      "global_load_dwordx4 %3, %16, off offset:144 sc0 sc1\n\t"
      "global_load_dwordx4 %4, %16, off offset:256 sc0 sc1\n\t"
      "global_load_dwordx4 %5, %16, off offset:272 sc0 sc1\n\t"
      "global_load_dwordx4 %6, %16, off offset:384 sc0 sc1\n\t"
      "global_load_dwordx4 %7, %16, off offset:400 sc0 sc1\n\t"
      "global_load_dwordx4 %8, %16, off offset:512 sc0 sc1\n\t"
      "global_load_dwordx4 %9, %16, off offset:528 sc0 sc1\n\t"
      "global_load_dwordx4 %10, %16, off offset:640 sc0 sc1\n\t"
      "global_load_dwordx4 %11, %16, off offset:656 sc0 sc1\n\t"
      "global_load_dwordx4 %12, %16, off offset:768 sc0 sc1\n\t"
      "global_load_dwordx4 %13, %16, off offset:784 sc0 sc1\n\t"
      "global_load_dwordx4 %14, %16, off offset:896 sc0 sc1\n\t"
      "global_load_dwordx4 %15, %16, off offset:912 sc0 sc1\n\t"
      "s_waitcnt vmcnt(0)"
      : "=v"(r[0]), "=v"(r[1]), "=v"(r[2]), "=v"(r[3]),
        "=v"(r[4]), "=v"(r[5]), "=v"(r[6]), "=v"(r[7]),
        "=v"(r[8]), "=v"(r[9]), "=v"(r[10]), "=v"(r[11]),
        "=v"(r[12]), "=v"(r[13]), "=v"(r[14]), "=v"(r[15])
      : "v"(p)
      : "memory");
}

__device__ __forceinline__ bool unpack_check(const uint4v r[16], unsigned tag16, frag_ab* a) {
  bool ok = true;
  #pragma unroll
  for (int kt = 0; kt < 8; ++kt) {
    #pragma unroll
    for (int j = 0; j < 8; ++j) {
      unsigned w = r[kt * 2 + (j >> 2)][j & 3];
      ok &= ((w >> 16) == tag16);
      a[kt][j] = (short)w;
    }
  }
  return ok;
}

__device__ __forceinline__ void read_state(const unsigned* p, unsigned tag16, frag_ab* a) {
  for (;;) {
    uint4v r[16];
    load16_sys(p, r);
    if (__all(unpack_check(r, tag16, a))) return;
  }
}

// poll 16 line-padded summary dwords (lane i checks producer i&15)
__device__ __forceinline__ void poll_summ(const unsigned* s, unsigned need, int lane) {
  const unsigned* p = s + (size_t)(lane & 15) * 16;
  while (!__all((int)ld_sys_u32(p) >= (int)need)) {}
}

// publish 4 tagged payload words (rows rr at stride HID)
__device__ __forceinline__ void publish4(unsigned* pp, unsigned tag16, const float* v) {
  #pragma unroll
  for (int rr = 0; rr < 4; ++rr)
    st_sys_u32(pp + (size_t)rr * HID, (tag16 << 16) | (unsigned)f2bf(v[rr]));
}

__global__ void __launch_bounds__(64, 1)
resrnn_kernel(const float* __restrict__ x,
              const float* __restrict__ W1, const float* __restrict__ U1, const float* __restrict__ b1,
              const float* __restrict__ W2, const float* __restrict__ U2, const float* __restrict__ b2,
              const float* __restrict__ W3, const float* __restrict__ U3, const float* __restrict__ V3,
              const float* __restrict__ b3,
              const float* __restrict__ G1, const float* __restrict__ bg1,
              const float* __restrict__ G2, const float* __restrict__ bg2,
              const float* __restrict__ O1, const float* __restrict__ O2, const float* __restrict__ bo,
              float* __restrict__ out,
              unsigned* __restrict__ h1buf,   // [BATCH][HID] tagged
              unsigned* __restrict__ h2r,     // [RING][BATCH][HID] tagged
              unsigned* __restrict__ h3r,     // [RING][BATCH][HID] tagged
              unsigned* __restrict__ summ,    // [3][NRG][16] pad16
              unsigned* __restrict__ done)    // [NRG] pad16, monotonic
{
  extern __shared__ char smem[];
  frag_ab* wf = (frag_ab*)smem;

  const int lane = (int)threadIdx.x;   // block = 1 wave of 64
  const int quad = lane >> 4;
  const int nn   = lane & 15;
  const int bid  = (int)blockIdx.x;

  if (bid < 64) {
    // ------------------------- RNN workgroup -------------------------
    const int rg = bid & 3;
    const int sl = bid >> 2;
    const int colbase = sl * 16;

    unsigned* sm1 = summ + ((size_t)(0 * NRG + rg) * 16 + sl) * 16;
    unsigned* sm2 = summ + ((size_t)(1 * NRG + rg) * 16 + sl) * 16;
    unsigned* sm3 = summ + ((size_t)(2 * NRG + rg) * 16 + sl) * 16;
    const unsigned* sb1 = summ + (size_t)(0 * NRG + rg) * 256;
    const unsigned* sb2 = summ + (size_t)(1 * NRG + rg) * 256;
    const unsigned* sb3 = summ + (size_t)(2 * NRG + rg) * 256;

    // ---- stage weights into LDS as bf16 B-fragments ----
    {
      const float* mats[9] = { W1, U1, W2, U2, W3, U3, V3, G1, G2 };
      const int    nkt[9]  = { 1, 8, 8, 8, 8, 8, 8, 16, 24 };
      int slot = 0;
      for (int m = 0; m < 9; ++m) {
        const float* W = mats[m];
        for (int kt = 0; kt < nkt[m]; ++kt) {
          frag_ab f;
          #pragma unroll
          for (int j = 0; j < 8; ++j) {
            int k = kt * 32 + quad * 8 + j;
            f[j] = (short)f2bf(W[(size_t)k * HID + colbase + nn]);
          }
          wf[slot * 64 + lane] = f;
          ++slot;
        }
      }
    }

    const float b1l  = b1[colbase + nn];
    const float b2l  = b2[colbase + nn];
    const float b3l  = b3[colbase + nn];
    const float bg1l = bg1[colbase + nn];
    const float bg2l = bg2[colbase + nn];

    frag_ab a1[8], a2[8], a3[8];
    const frag_ab zf = {0,0,0,0,0,0,0,0};
    #pragma unroll
    for (int i = 0; i < 8; ++i) { a1[i] = zf; a2[i] = zf; a3[i] = zf; }
    float h2l[4] = {0.f,0.f,0.f,0.f};
    float h3l[4] = {0.f,0.f,0.f,0.f};
    float z1l[4] = {1.f,1.f,1.f,1.f};
    float z2l[4] = {1.f,1.f,1.f,1.f};

    const float*    xrow  = x + (size_t)(rg * 16 + nn) * T_LEN * DIM + quad * 8;
    unsigned*       h1pub = h1buf + ((size_t)(rg * 16 + quad * 4)) * HID + colbase + nn;
    const unsigned* h1rd  = h1buf + ((size_t)(rg * 16 + nn)) * HID + quad * 8;

    for (int t = 0; t < T_LEN; ++t) {
      const unsigned tag  = (unsigned)(t + 1);
      const int      slot = t & (RING - 1);

      // ring back-pressure (out-wg lags ~1 step << RING; rarely spins)
      if (t >= RING) {
        const unsigned need = (unsigned)(t - RING + 1);
        while ((int)ld_sys_u32(done + rg * 16) < (int)need) {}
      }

      // ---- stage 1: h1 = tanh(x@W1 + h1@U1 + b1) ----
      frag_cd p1a = {0.f,0.f,0.f,0.f}, p1b = {0.f,0.f,0.f,0.f};
      {
        const float* xp = xrow + (size_t)t * DIM;
        float4v xa = *(const float4v*)xp;
        float4v xb = *(const float4v*)(xp + 4);
        frag_ab xf;
        #pragma unroll
        for (int j = 0; j < 4; ++j) { xf[j] = (short)f2bf(xa[j]); xf[4 + j] = (short)f2bf(xb[j]); }
        p1a = MFMA16(xf, wf[S_W1 * 64 + lane], p1a);
      }
      #pragma unroll
      for (int kt = 0; kt < 4; ++kt) p1a = MFMA16(a1[kt], wf[(S_U1 + kt) * 64 + lane], p1a);
      #pragma unroll
      for (int kt = 4; kt < 8; ++kt) p1b = MFMA16(a1[kt], wf[(S_U1 + kt) * 64 + lane], p1b);
      {
        float v[4];
        #pragma unroll
        for (int rr = 0; rr < 4; ++rr) v[rr] = fast_tanh(p1a[rr] + p1b[rr] + b1l);
        publish4(h1pub, tag, v);
      }
      wait_vm0();                       // payload at LLC before summary
      if (lane == 0) st_sys_u32(sm1, tag);

      // overlap: h2@U2 with old h2 frags (independent of h1(t))
      frag_cd p2a = {0.f,0.f,0.f,0.f}, p2b = {0.f,0.f,0.f,0.f};
      #pragma unroll
      for (int kt = 0; kt < 4; ++kt) p2a = MFMA16(a2[kt], wf[(S_U2 + kt) * 64 + lane], p2a);
      #pragma unroll
      for (int kt = 4; kt < 8; ++kt) p2b = MFMA16(a2[kt], wf[(S_U2 + kt) * 64 + lane], p2b);

      poll_summ(sb1, tag, lane);
      read_state(h1rd, tag, a1);        // gather full h1(t)

      // ---- stage 2: h2 = z1*tanh(h1@W2 + h2@U2 + b2) + (1-z1)*h2 ----
      #pragma unroll
      for (int kt = 0; kt < 4; ++kt) p2a = MFMA16(a1[kt], wf[(S_W2 + kt) * 64 + lane], p2a);
      #pragma unroll
      for (int kt = 4; kt < 8; ++kt) p2b = MFMA16(a1[kt], wf[(S_W2 + kt) * 64 + lane], p2b);
      #pragma unroll
      for (int rr = 0; rr < 4; ++rr) {
        float c = fast_tanh(p2a[rr] + p2b[rr] + b2l);
        h2l[rr] = z1l[rr] * c + (1.f - z1l[rr]) * h2l[rr];
      }
      publish4(h2r + ((size_t)slot * BATCH + rg * 16 + quad * 4) * HID + colbase + nn, tag, h2l);
      wait_vm0();
      if (lane == 0) st_sys_u32(sm2, tag);

      // overlap: h3@U3 (old h3), h1@V3, G1 h1-part (independent of h2(t))
      frag_cd p3u = {0.f,0.f,0.f,0.f}, p3v = {0.f,0.f,0.f,0.f}, pg1a = {0.f,0.f,0.f,0.f};
      #pragma unroll
      for (int kt = 0; kt < 8; ++kt) p3u = MFMA16(a3[kt], wf[(S_U3 + kt) * 64 + lane], p3u);
      #pragma unroll
      for (int kt = 0; kt < 8; ++kt) p3v = MFMA16(a1[kt], wf[(S_V3 + kt) * 64 + lane], p3v);
      #pragma unroll
      for (int kt = 0; kt < 8; ++kt) pg1a = MFMA16(a1[kt], wf[(S_G1 + kt) * 64 + lane], pg1a);

      poll_summ(sb2, tag, lane);
      read_state(h2r + ((size_t)slot * BATCH + rg * 16 + nn) * HID + quad * 8, tag, a2);

      // ---- stage 3: h3 = z2*tanh(h2@W3 + h3@U3 + h1@V3 + b3) + (1-z2)*h3 ----
      frag_cd p3w = {0.f,0.f,0.f,0.f};
      #pragma unroll
      for (int kt = 0; kt < 8; ++kt) p3w = MFMA16(a2[kt], wf[(S_W3 + kt) * 64 + lane], p3w);
      #pragma unroll
      for (int rr = 0; rr < 4; ++rr) {
        float c = fast_tanh(p3u[rr] + p3v[rr] + p3w[rr] + b3l);
        h3l[rr] = z2l[rr] * c + (1.f - z2l[rr]) * h3l[rr];
      }
      publish4(h3r + ((size_t)slot * BATCH + rg * 16 + quad * 4) * HID + colbase + nn, tag, h3l);
      wait_vm0();
      if (lane == 0) st_sys_u32(sm3, tag);

      // overlap: G1 h2-part, G2 h1+h2 parts (independent of h3(t))
      frag_cd pg1b = {0.f,0.f,0.f,0.f}, pg2a = {0.f,0.f,0.f,0.f}, pg2b = {0.f,0.f,0.f,0.f};
      #pragma unroll
      for (int kt = 0; kt < 8; ++kt) pg1b = MFMA16(a2[kt], wf[(S_G1 + 8 + kt) * 64 + lane], pg1b);
      #pragma unroll
      for (int kt = 0; kt < 8; ++kt) pg2a = MFMA16(a1[kt], wf[(S_G2 + kt) * 64 + lane], pg2a);
      #pragma unroll
      for (int kt = 0; kt < 8; ++kt) pg2b = MFMA16(a2[kt], wf[(S_G2 + 8 + kt) * 64 + lane], pg2b);

      poll_summ(sb3, tag, lane);
      read_state(h3r + ((size_t)slot * BATCH + rg * 16 + nn) * HID + quad * 8, tag, a3);

      // ---- gates ----
      frag_cd pg2c = {0.f,0.f,0.f,0.f};
      #pragma unroll
      for (int kt = 0; kt < 8; ++kt) pg2c = MFMA16(a3[kt], wf[(S_G2 + 16 + kt) * 64 + lane], pg2c);
      #pragma unroll
      for (int rr = 0; rr < 4; ++rr) {
        float z1n = fast_sigmoid(pg1a[rr] + pg1b[rr] + bg1l);
        float z2n = fast_sigmoid(pg2a[rr] + pg2b[rr] + pg2c[rr] + bg2l);
        z1l[rr] = z1n * z2n;
        z2l[rr] = z2n;
      }
    }
  } else {
    // --------------------- output-projection workgroup ---------------------
    const int rg = bid - 64;
    const unsigned* sb2 = summ + (size_t)(1 * NRG + rg) * 256;
    const unsigned* sb3 = summ + (size_t)(2 * NRG + rg) * 256;
    {
      const float* mats[2] = { O1, O2 };
      for (int m = 0; m < 2; ++m)
        for (int nt = 0; nt < 2; ++nt)
          for (int kt = 0; kt < 8; ++kt) {
            frag_ab f;
            #pragma unroll
            for (int j = 0; j < 8; ++j) {
              int k = kt * 32 + quad * 8 + j;
              f[j] = (short)f2bf(mats[m][(size_t)k * DIM + nt * 16 + nn]);
            }
            wf[(m * 16 + nt * 8 + kt) * 64 + lane] = f;
          }
    }
    const float bo0 = bo[nn];
    const float bo1 = bo[16 + nn];

    for (int t = 0; t < T_LEN; ++t) {
      const unsigned tag  = (unsigned)(t + 1);
      const int      slot = t & (RING - 1);
      const unsigned* g2p = h2r + ((size_t)slot * BATCH + rg * 16 + nn) * HID + quad * 8;
      const unsigned* g3p = h3r + ((size_t)slot * BATCH + rg * 16 + nn) * HID + quad * 8;

      poll_summ(sb2, tag, lane);
      poll_summ(sb3, tag, lane);
      frag_ab a2[8], a3[8];
      read_state(g2p, tag, a2);
      read_state(g3p, tag, a3);

      frag_cd o0 = {0.f,0.f,0.f,0.f}, o1 = {0.f,0.f,0.f,0.f};
      #pragma unroll
      for (int kt = 0; kt < 8; ++kt) {
        o0 = MFMA16(a2[kt], wf[(0 * 16 + 0 * 8 + kt) * 64 + lane], o0);
        o1 = MFMA16(a2[kt], wf[(0 * 16 + 1 * 8 + kt) * 64 + lane], o1);
        o0 = MFMA16(a3[kt], wf[(1 * 16 + 0 * 8 + kt) * 64 + lane], o0);
        o1 = MFMA16(a3[kt], wf[(1 * 16 + 1 * 8 + kt) * 64 + lane], o1);
      }
      #pragma unroll
      for (int rr = 0; rr < 4; ++rr) {
        float* op = out + ((size_t)(rg * 16 + quad * 4 + rr) * T_LEN + t) * DIM;
        op[nn]      = o0[rr] + bo0;
        op[16 + nn] = o1[rr] + bo1;
      }
      // ring data consumed into registers (loads retired in read_state)
      if (lane == 0) st_sys_u32(done + rg * 16, tag);
    }
  }
}

extern "C" void kernel_launch(void* const* d_in, const int* in_sizes, int n_in,
                              void* d_out, int out_size, void* d_ws, size_t ws_size,
                              hipStream_t stream)
{
  (void)in_sizes; (void)n_in; (void)out_size; (void)ws_size;

  const float* x   = (const float*)d_in[0];
  const float* W1  = (const float*)d_in[1];
  const float* U1  = (const float*)d_in[2];
  const float* b1  = (const float*)d_in[3];
  const float* W2  = (const float*)d_in[4];
  const float* U2  = (const float*)d_in[5];
  const float* b2  = (const float*)d_in[6];
  const float* W3  = (const float*)d_in[7];
  const float* U3  = (const float*)d_in[8];
  const float* V3  = (const float*)d_in[9];
  const float* b3  = (const float*)d_in[10];
  const float* G1  = (const float*)d_in[11];
  const float* bg1 = (const float*)d_in[12];
  const float* G2  = (const float*)d_in[13];
  const float* bg2 = (const float*)d_in[14];
  const float* O1  = (const float*)d_in[15];
  const float* O2  = (const float*)d_in[16];
  const float* bo  = (const float*)d_in[17];

  char* ws = (char*)d_ws;
  unsigned* h1buf = (unsigned*)(ws + H1_OFF);
  unsigned* h2r   = (unsigned*)(ws + H2R_OFF);
  unsigned* h3r   = (unsigned*)(ws + H3R_OFF);
  unsigned* summ  = (unsigned*)(ws + SUM_OFF);
  unsigned* done  = summ + SUM_DW;

  // summaries + done must start at 0 (monotonic >= checks; ws poisoned 0xAA).
  // tagged payload buffers need no init (poison tag 0xAAAA never matches).
  hipMemsetAsync(summ, 0, CTL_SZ, stream);

  (void)hipFuncSetAttribute((const void*)resrnn_kernel,
                            hipFuncAttributeMaxDynamicSharedMemorySize, LDS_BYTES);

  resrnn_kernel<<<dim3(68), dim3(64), LDS_BYTES, stream>>>(
      x, W1, U1, b1, W2, U2, b2, W3, U3, V3, b3,
      G1, bg1, G2, bg2, O1, O2, bo,
      (float*)d_out, h1buf, h2r, h3r, summ, done);
}

// Round 5
// 13817.047 us; speedup vs baseline: 1.9685x; 1.4437x over previous
//
#include <hip/hip_runtime.h>

// ---------------------------------------------------------------------------
// ResRNN: sequential gated residual RNN, B=64, T=2048, D=32, H=256 (fp32).
//
// R5: direct-payload polling + 2-hop critical cycle.
//  * Topology: 64 RNN wgs = 4 row-groups x 16 col-slices, weights in LDS
//    (89 KB/CU); 4 out-wgs on a depth-32 ring.
//  * R4 post-mortem: hop = 3 LLC round-trips (store-ack wait + summary store
//    + summary poll + payload read) ~3.2us. R5 drops the summary layer:
//    payload words (tag<<16)|bf16 are self-validating; producers fire-and-
//    forget, consumers poll payload directly (16x dwordx4, one vmcnt/retry).
//  * Cycle restructure: per-step dependence cycle is h2->h3->gates->h2' =
//    2 hops; the h1 chain (1 hop/step) runs one iteration AHEAD (lookahead
//    publish, polled during the h3 wait). W2@h1(t+1)+U2@h2(t) precomputed
//    off-cycle so post-gate h2-update is ~40cyc.
//  * Skew bound: any wg entering iter T+2 has passed poll_h2(tag T+2), which
//    requires all wgs' iter T+1 step-1, which requires their poll_h1(tag T+2)
//    -> overwriting h1 slot parity is safe; rings guarded by amortized
//    back-pressure (every 8 steps).
// ---------------------------------------------------------------------------

#define T_LEN 2048
#define BATCH 64
#define DIM   32
#define HID   256
#define NRG   4
#define RING  32

typedef short    frag_ab __attribute__((ext_vector_type(8)));   // 8 x bf16
typedef float    frag_cd __attribute__((ext_vector_type(4)));   // 4 x f32
typedef float    float4v __attribute__((ext_vector_type(4)));
typedef unsigned uint4v  __attribute__((ext_vector_type(4)));

#define MFMA16(a, b, c) __builtin_amdgcn_mfma_f32_16x16x32_bf16((a), (b), (c), 0, 0, 0)

// LDS slot bases (1 slot = one K-tile of B-frags = 64 lanes * 16 B = 1 KB)
#define S_W1 0
#define S_U1 1
#define S_W2 9
#define S_U2 17
#define S_W3 25
#define S_U3 33
#define S_V3 41
#define S_G1 49   // 49..56 h1-part, 57..64 h2-part
#define S_G2 65   // 65..72 h1, 73..80 h2, 81..88 h3
#define NSLOT 89
#define LDS_BYTES (NSLOT * 64 * 16)   // 91,136 B

// workspace layout
#define H1_OFF   0
#define H1_SZ    (2 * BATCH * HID * 4)              // 128 KB (2-deep)
#define H2R_OFF  (H1_OFF + H1_SZ)
#define H2R_SZ   (RING * BATCH * HID * 4)           // 2 MB
#define H3R_OFF  (H2R_OFF + H2R_SZ)
#define H3R_SZ   (RING * BATCH * HID * 4)           // 2 MB
#define CTL_OFF  (H3R_OFF + H3R_SZ)
#define CTL_SZ   (NRG * 16 * 4)                     // done[rg] pad 16 dw

__device__ __forceinline__ unsigned short f2bf(float f) {
  unsigned u = __builtin_bit_cast(unsigned, f);
  u = (u + 0x7FFFu + ((u >> 16) & 1u)) >> 16;   // RNE
  return (unsigned short)u;
}

__device__ __forceinline__ float fast_tanh(float x) {
  x = fminf(fmaxf(x, -15.f), 15.f);
  float e = __expf(2.f * x);
  return (e - 1.f) / (e + 1.f);
}

__device__ __forceinline__ float fast_sigmoid(float x) {
  x = fminf(fmaxf(x, -30.f), 30.f);
  return 1.f / (1.f + __expf(-x));
}

// ---- LLC-visible memory ops (sc0 sc1) ----
__device__ __forceinline__ void st_sys_u32(unsigned* p, unsigned v) {
  asm volatile("global_store_dword %0, %1, off sc0 sc1" :: "v"(p), "v"(v) : "memory");
}
__device__ __forceinline__ unsigned ld_sys_u32(const unsigned* p) {
  unsigned r;
  asm volatile("global_load_dword %0, %1, off sc0 sc1\n\t"
               "s_waitcnt vmcnt(0)"
               : "=v"(r) : "v"(p) : "memory");
  return r;
}

// one-shot payload read: 16 x dwordx4 (sc0 sc1) pipelined, single vmcnt.
// p = base + row*HID + quad*8 (dwords); offsets kt*128 + {0,16} bytes.
__device__ __forceinline__ void load16_sys(const unsigned* p, uint4v r[16]) {
  asm volatile(
      "global_load_dwordx4 %0, %16, off sc0 sc1\n\t"
      "global_load_dwordx4 %1, %16, off offset:16 sc0 sc1\n\t"
      "global_load_dwordx4 %2, %16, off offset:128 sc0 sc1\n\t"
      "global_load_dwordx4 %3, %16, off offset:144 sc0 sc1\n\t"
      "global_load_dwordx4 %4, %16, off offset:256 sc0 sc1\n\t"
      "global_load_dwordx4 %5, %16, off offset:272 sc0 sc1\n\t"
      "global_load_dwordx4 %6, %16, off offset:384 sc0 sc1\n\t"
      "global_load_dwordx4 %7, %16, off offset:400 sc0 sc1\n\t"
      "global_load_dwordx4 %8, %16, off offset:512 sc0 sc1\n\t"
      "global_load_dwordx4 %9, %16, off offset:528 sc0 sc1\n\t"
      "global_load_dwordx4 %10, %16, off offset:640 sc0 sc1\n\t"
      "global_load_dwordx4 %11, %16, off offset:656 sc0 sc1\n\t"
      "global_load_dwordx4 %12, %16, off offset:768 sc0 sc1\n\t"
      "global_load_dwordx4 %13, %16, off offset:784 sc0 sc1\n\t"
      "global_load_dwordx4 %14, %16, off offset:896 sc0 sc1\n\t"
      "global_load_dwordx4 %15, %16, off offset:912 sc0 sc1\n\t"
      "s_waitcnt vmcnt(0)"
      : "=v"(r[0]), "=v"(r[1]), "=v"(r[2]), "=v"(r[3]),
        "=v"(r[4]), "=v"(r[5]), "=v"(r[6]), "=v"(r[7]),
        "=v"(r[8]), "=v"(r[9]), "=v"(r[10]), "=v"(r[11]),
        "=v"(r[12]), "=v"(r[13]), "=v"(r[14]), "=v"(r[15])
      : "v"(p)
      : "memory");
}

__device__ __forceinline__ bool unpack_check(const uint4v r[16], unsigned tag16, frag_ab* a) {
  bool ok = true;
  #pragma unroll
  for (int kt = 0; kt < 8; ++kt) {
    #pragma unroll
    for (int j = 0; j < 8; ++j) {
      unsigned w = r[kt * 2 + (j >> 2)][j & 3];
      ok &= ((w >> 16) == tag16);
      a[kt][j] = (short)w;
    }
  }
  return ok;
}

// poll payload until all 64 dwords/lane carry tag16 (no summary layer)
__device__ __forceinline__ void read_state(const unsigned* p, unsigned tag16, frag_ab* a) {
  for (;;) {
    uint4v r[16];
    load16_sys(p, r);
    if (__all(unpack_check(r, tag16, a))) return;
  }
}

// publish 4 tagged payload words (rows rr at stride HID), fire-and-forget
__device__ __forceinline__ void publish4(unsigned* pp, unsigned tag16, const float* v) {
  #pragma unroll
  for (int rr = 0; rr < 4; ++rr)
    st_sys_u32(pp + (size_t)rr * HID, (tag16 << 16) | (unsigned)f2bf(v[rr]));
}

__global__ void __launch_bounds__(64, 1)
resrnn_kernel(const float* __restrict__ x,
              const float* __restrict__ W1, const float* __restrict__ U1, const float* __restrict__ b1,
              const float* __restrict__ W2, const float* __restrict__ U2, const float* __restrict__ b2,
              const float* __restrict__ W3, const float* __restrict__ U3, const float* __restrict__ V3,
              const float* __restrict__ b3,
              const float* __restrict__ G1, const float* __restrict__ bg1,
              const float* __restrict__ G2, const float* __restrict__ bg2,
              const float* __restrict__ O1, const float* __restrict__ O2, const float* __restrict__ bo,
              float* __restrict__ out,
              unsigned* __restrict__ h1buf,   // [2][BATCH][HID] tagged
              unsigned* __restrict__ h2r,     // [RING][BATCH][HID] tagged
              unsigned* __restrict__ h3r,     // [RING][BATCH][HID] tagged
              unsigned* __restrict__ done)    // [NRG] pad16, monotonic
{
  extern __shared__ char smem[];
  frag_ab* wf = (frag_ab*)smem;

  const int lane = (int)threadIdx.x;   // block = 1 wave of 64
  const int quad = lane >> 4;
  const int nn   = lane & 15;
  const int bid  = (int)blockIdx.x;

  if (bid < 64) {
    // ------------------------- RNN workgroup -------------------------
    const int rg = bid & 3;
    const int sl = bid >> 2;
    const int colbase = sl * 16;

    // ---- stage weights into LDS as bf16 B-fragments ----
    {
      const float* mats[9] = { W1, U1, W2, U2, W3, U3, V3, G1, G2 };
      const int    nkt[9]  = { 1, 8, 8, 8, 8, 8, 8, 16, 24 };
      int slot = 0;
      for (int m = 0; m < 9; ++m) {
        const float* W = mats[m];
        for (int kt = 0; kt < nkt[m]; ++kt) {
          frag_ab f;
          #pragma unroll
          for (int j = 0; j < 8; ++j) {
            int k = kt * 32 + quad * 8 + j;
            f[j] = (short)f2bf(W[(size_t)k * HID + colbase + nn]);
          }
          wf[slot * 64 + lane] = f;
          ++slot;
        }
      }
    }

    const float b1l  = b1[colbase + nn];
    const float b2l  = b2[colbase + nn];
    const float b3l  = b3[colbase + nn];
    const float bg1l = bg1[colbase + nn];
    const float bg2l = bg2[colbase + nn];

    const frag_ab zf = {0,0,0,0,0,0,0,0};
    frag_ab a1n[8], a3old[8];
    #pragma unroll
    for (int i = 0; i < 8; ++i) { a1n[i] = zf; a3old[i] = zf; }
    float h2l[4] = {0.f,0.f,0.f,0.f};
    float h3l[4] = {0.f,0.f,0.f,0.f};
    float z1l[4] = {1.f,1.f,1.f,1.f};
    float z2l[4] = {1.f,1.f,1.f,1.f};

    const float*    xrow  = x + (size_t)(rg * 16 + nn) * T_LEN * DIM + quad * 8;
    unsigned*       h1pub = h1buf + ((size_t)(rg * 16 + quad * 4)) * HID + colbase + nn;
    const unsigned* h1rd  = h1buf + ((size_t)(rg * 16 + nn)) * HID + quad * 8;
    const size_t    h1st  = (size_t)BATCH * HID;   // slot stride (dwords)

    // ---- prologue: h1(0) = tanh(x(0)@W1 + b1), publish slot0 tag1 ----
    {
      frag_cd p = {0.f,0.f,0.f,0.f};
      float4v xa = *(const float4v*)xrow;
      float4v xb = *(const float4v*)(xrow + 4);
      frag_ab xf;
      #pragma unroll
      for (int j = 0; j < 4; ++j) { xf[j] = (short)f2bf(xa[j]); xf[4 + j] = (short)f2bf(xb[j]); }
      p = MFMA16(xf, wf[S_W1 * 64 + lane], p);
      float v[4];
      #pragma unroll
      for (int rr = 0; rr < 4; ++rr) v[rr] = fast_tanh(p[rr] + b1l);
      publish4(h1pub, 1u, v);
    }
    read_state(h1rd, 1u, a1n);          // a1n = h1(0)

    // p2acc = W2@h1(0) + U2@h2(-1=0)
    frag_cd p2a = {0.f,0.f,0.f,0.f}, p2b = {0.f,0.f,0.f,0.f};
    #pragma unroll
    for (int kt = 0; kt < 4; ++kt) p2a = MFMA16(a1n[kt], wf[(S_W2 + kt) * 64 + lane], p2a);
    #pragma unroll
    for (int kt = 4; kt < 8; ++kt) p2b = MFMA16(a1n[kt], wf[(S_W2 + kt) * 64 + lane], p2b);

    for (int t = 0; t < T_LEN; ++t) {
      const unsigned tag  = (unsigned)(t + 1);
      const int      slot = t & (RING - 1);

      // amortized ring back-pressure: cover slots for steps t..t+7
      if (t >= RING && (t & 7) == 0) {
        const unsigned need = (unsigned)(t - RING + 8);
        while (ld_sys_u32(done + rg * 16) < need) {}
      }

      // ---- 1. h2(t) update + publish (p2acc ready, z1 from gates(t-1)) ----
      #pragma unroll
      for (int rr = 0; rr < 4; ++rr) {
        float c = fast_tanh(p2a[rr] + p2b[rr] + b2l);
        h2l[rr] = z1l[rr] * c + (1.f - z1l[rr]) * h2l[rr];
      }
      publish4(h2r + ((size_t)slot * BATCH + rg * 16 + quad * 4) * HID + colbase + nn, tag, h2l);

      // ---- 2. h1 lookahead: h1(t+1) = tanh(x(t+1)@W1 + U1@h1(t) + b1) ----
      if (t + 1 < T_LEN) {
        frag_cd p = {0.f,0.f,0.f,0.f};
        const float* xp = xrow + (size_t)(t + 1) * DIM;
        float4v xa = *(const float4v*)xp;
        float4v xb = *(const float4v*)(xp + 4);
        frag_ab xf;
        #pragma unroll
        for (int j = 0; j < 4; ++j) { xf[j] = (short)f2bf(xa[j]); xf[4 + j] = (short)f2bf(xb[j]); }
        p = MFMA16(xf, wf[S_W1 * 64 + lane], p);
        #pragma unroll
        for (int kt = 0; kt < 8; ++kt) p = MFMA16(a1n[kt], wf[(S_U1 + kt) * 64 + lane], p);
        float v[4];
        #pragma unroll
        for (int rr = 0; rr < 4; ++rr) v[rr] = fast_tanh(p[rr] + b1l);
        publish4(h1pub + ((size_t)((t + 1) & 1)) * h1st, tag + 1u, v);
      }

      // ---- 3. precompute (indep of h2(t), h3(t)) ----
      frag_cd p3u = {0.f,0.f,0.f,0.f}, pg1a = {0.f,0.f,0.f,0.f}, pg2a = {0.f,0.f,0.f,0.f};
      #pragma unroll
      for (int kt = 0; kt < 8; ++kt) p3u = MFMA16(a3old[kt], wf[(S_U3 + kt) * 64 + lane], p3u);
      #pragma unroll
      for (int kt = 0; kt < 8; ++kt) p3u = MFMA16(a1n[kt], wf[(S_V3 + kt) * 64 + lane], p3u);
      #pragma unroll
      for (int kt = 0; kt < 8; ++kt) pg1a = MFMA16(a1n[kt], wf[(S_G1 + kt) * 64 + lane], pg1a);
      #pragma unroll
      for (int kt = 0; kt < 8; ++kt) pg2a = MFMA16(a1n[kt], wf[(S_G2 + kt) * 64 + lane], pg2a);

      // ---- 4. poll h2(t) full ----
      frag_ab a2[8];
      read_state(h2r + ((size_t)slot * BATCH + rg * 16 + nn) * HID + quad * 8, tag, a2);

      // ---- 5. h3(t) update + publish ----
      {
        frag_cd p3 = p3u;
        #pragma unroll
        for (int kt = 0; kt < 8; ++kt) p3 = MFMA16(a2[kt], wf[(S_W3 + kt) * 64 + lane], p3);
        #pragma unroll
        for (int rr = 0; rr < 4; ++rr) {
          float c = fast_tanh(p3[rr] + b3l);
          h3l[rr] = z2l[rr] * c + (1.f - z2l[rr]) * h3l[rr];
        }
        publish4(h3r + ((size_t)slot * BATCH + rg * 16 + quad * 4) * HID + colbase + nn, tag, h3l);
      }

      // ---- 6. precompute next-iter p2acc + gate h2-parts; poll h1(t+1) ----
      frag_cd pg1b = {0.f,0.f,0.f,0.f}, pg2b = {0.f,0.f,0.f,0.f};
      #pragma unroll
      for (int kt = 0; kt < 8; ++kt) pg1b = MFMA16(a2[kt], wf[(S_G1 + 8 + kt) * 64 + lane], pg1b);
      #pragma unroll
      for (int kt = 0; kt < 8; ++kt) pg2b = MFMA16(a2[kt], wf[(S_G2 + 8 + kt) * 64 + lane], pg2b);
      p2a = (frag_cd){0.f,0.f,0.f,0.f};
      p2b = (frag_cd){0.f,0.f,0.f,0.f};
      #pragma unroll
      for (int kt = 0; kt < 4; ++kt) p2a = MFMA16(a2[kt], wf[(S_U2 + kt) * 64 + lane], p2a);
      #pragma unroll
      for (int kt = 4; kt < 8; ++kt) p2b = MFMA16(a2[kt], wf[(S_U2 + kt) * 64 + lane], p2b);
      if (t + 1 < T_LEN) {
        read_state(h1rd + ((size_t)((t + 1) & 1)) * h1st, tag + 1u, a1n);  // a1n = h1(t+1)
        #pragma unroll
        for (int kt = 0; kt < 4; ++kt) p2a = MFMA16(a1n[kt], wf[(S_W2 + kt) * 64 + lane], p2a);
        #pragma unroll
        for (int kt = 4; kt < 8; ++kt) p2b = MFMA16(a1n[kt], wf[(S_W2 + kt) * 64 + lane], p2b);
      }

      // ---- 7. poll h3(t) full ----
      read_state(h3r + ((size_t)slot * BATCH + rg * 16 + nn) * HID + quad * 8, tag, a3old);

      // ---- 8. gates(t) ----
      frag_cd pg2c = {0.f,0.f,0.f,0.f};
      #pragma unroll
      for (int kt = 0; kt < 8; ++kt) pg2c = MFMA16(a3old[kt], wf[(S_G2 + 16 + kt) * 64 + lane], pg2c);
      #pragma unroll
      for (int rr = 0; rr < 4; ++rr) {
        float z1n = fast_sigmoid(pg1a[rr] + pg1b[rr] + bg1l);
        float z2n = fast_sigmoid(pg2a[rr] + pg2b[rr] + pg2c[rr] + bg2l);
        z1l[rr] = z1n * z2n;
        z2l[rr] = z2n;
      }
    }
  } else {
    // --------------------- output-projection workgroup ---------------------
    const int rg = bid - 64;
    {
      const float* mats[2] = { O1, O2 };
      for (int m = 0; m < 2; ++m)
        for (int nt = 0; nt < 2; ++nt)
          for (int kt = 0; kt < 8; ++kt) {
            frag_ab f;
            #pragma unroll
            for (int j = 0; j < 8; ++j) {
              int k = kt * 32 + quad * 8 + j;
              f[j] = (short)f2bf(mats[m][(size_t)k * DIM + nt * 16 + nn]);
            }
            wf[(m * 16 + nt * 8 + kt) * 64 + lane] = f;
          }
    }
    const float bo0 = bo[nn];
    const float bo1 = bo[16 + nn];

    for (int t = 0; t < T_LEN; ++t) {
      const unsigned tag  = (unsigned)(t + 1);
      const int      slot = t & (RING - 1);
      const unsigned* g2p = h2r + ((size_t)slot * BATCH + rg * 16 + nn) * HID + quad * 8;
      const unsigned* g3p = h3r + ((size_t)slot * BATCH + rg * 16 + nn) * HID + quad * 8;

      frag_ab a2[8], a3[8];
      for (;;) {   // combined direct-payload poll of h2(t), h3(t)
        uint4v r2[16], r3[16];
        load16_sys(g2p, r2);
        load16_sys(g3p, r3);
        bool ok = unpack_check(r2, tag, a2);
        ok &= unpack_check(r3, tag, a3);
        if (__all(ok)) break;
      }

      frag_cd o0 = {0.f,0.f,0.f,0.f}, o1 = {0.f,0.f,0.f,0.f};
      #pragma unroll
      for (int kt = 0; kt < 8; ++kt) {
        o0 = MFMA16(a2[kt], wf[(0 * 16 + 0 * 8 + kt) * 64 + lane], o0);
        o1 = MFMA16(a2[kt], wf[(0 * 16 + 1 * 8 + kt) * 64 + lane], o1);
        o0 = MFMA16(a3[kt], wf[(1 * 16 + 0 * 8 + kt) * 64 + lane], o0);
        o1 = MFMA16(a3[kt], wf[(1 * 16 + 1 * 8 + kt) * 64 + lane], o1);
      }
      #pragma unroll
      for (int rr = 0; rr < 4; ++rr) {
        float* op = out + ((size_t)(rg * 16 + quad * 4 + rr) * T_LEN + t) * DIM;
        op[nn]      = o0[rr] + bo0;
        op[16 + nn] = o1[rr] + bo1;
      }
      // ring data consumed into registers -> free slot
      if (lane == 0) st_sys_u32(done + rg * 16, tag);
    }
  }
}

extern "C" void kernel_launch(void* const* d_in, const int* in_sizes, int n_in,
                              void* d_out, int out_size, void* d_ws, size_t ws_size,
                              hipStream_t stream)
{
  (void)in_sizes; (void)n_in; (void)out_size; (void)ws_size;

  const float* x   = (const float*)d_in[0];
  const float* W1  = (const float*)d_in[1];
  const float* U1  = (const float*)d_in[2];
  const float* b1  = (const float*)d_in[3];
  const float* W2  = (const float*)d_in[4];
  const float* U2  = (const float*)d_in[5];
  const float* b2  = (const float*)d_in[6];
  const float* W3  = (const float*)d_in[7];
  const float* U3  = (const float*)d_in[8];
  const float* V3  = (const float*)d_in[9];
  const float* b3  = (const float*)d_in[10];
  const float* G1  = (const float*)d_in[11];
  const float* bg1 = (const float*)d_in[12];
  const float* G2  = (const float*)d_in[13];
  const float* bg2 = (const float*)d_in[14];
  const float* O1  = (const float*)d_in[15];
  const float* O2  = (const float*)d_in[16];
  const float* bo  = (const float*)d_in[17];

  char* ws = (char*)d_ws;
  unsigned* h1buf = (unsigned*)(ws + H1_OFF);
  unsigned* h2r   = (unsigned*)(ws + H2R_OFF);
  unsigned* h3r   = (unsigned*)(ws + H3R_OFF);
  unsigned* done  = (unsigned*)(ws + CTL_OFF);

  // done[] must start at 0 (ws poisoned 0xAA). Tagged payload buffers need
  // no init (poison tag 0xAAAA never matches a real tag <= 2049).
  hipMemsetAsync(done, 0, CTL_SZ, stream);

  (void)hipFuncSetAttribute((const void*)resrnn_kernel,
                            hipFuncAttributeMaxDynamicSharedMemorySize, LDS_BYTES);

  resrnn_kernel<<<dim3(68), dim3(64), LDS_BYTES, stream>>>(
      x, W1, U1, b1, W2, U2, b2, W3, U3, V3, b3,
      G1, bg1, G2, bg2, O1, O2, bo,
      (float*)d_out, h1buf, h2r, h3r, done);
}